// Round 7
// baseline (25.847 us; speedup 1.0000x reference)
//
#include <hip/hip_runtime.h>

#define NB 4
#define NS 1024
#define NE 128
#define NH 16
#define ND 8

typedef __attribute__((ext_vector_type(4))) _Float16 half4v;
typedef __attribute__((ext_vector_type(8))) _Float16 half8v;
typedef __attribute__((ext_vector_type(2))) _Float16 half2v;
typedef __attribute__((ext_vector_type(4))) float float4v;

// 2^x with BOTH branches native: builtin v_exp_f32 if available, else
// __expf(ln2*x) = v_mul_f32 + v_exp_f32 (never the ocml libm path).
#if __has_builtin(__builtin_amdgcn_exp2f)
#define EXP2F(x) __builtin_amdgcn_exp2f(x)
#else
#define EXP2F(x) __expf(0.69314718055994531f * (x))
#endif

// sqrt(log2(e)/sqrt(8)): both QK^T operands carry this -> MFMA out feeds 2^x directly
#define SQRT_ALPHA 0.71423656f

// ---------------------------------------------------------------------------
// Fused quantum-layer + self-attention via f16 MFMA, key-split for occupancy.
// proj[0]=g1*...*g7, proj[w]=g0*...*gw with g_j=cos(x_j+phi_j)  (CNOTs only
// permute a product distribution -> closed form; verified in round 1).
// S^T = K.Q^T via mfma 16x16x16: lane holds P[q=l&15][keys (l>>4)*4+r] ->
// exactly the PV A-fragment after exp2+cvt_pkrtz (no LDS bounce for P).
// V staged transposed with a ones-row (col 8 of output = softmax denom).
// Block = 1024 thr = 16 waves: wave w handles q-subtile (w&7), key half (w>>3).
// Key-half partials (unnormalized, incl. denom col) combined via LDS scratch.
// 32 waves/CU resident (2 blocks x 16 waves).
// ---------------------------------------------------------------------------
__global__ __launch_bounds__(1024)
void qattn_kernel(const float* __restrict__ x, const float* __restrict__ phi,
                  float* __restrict__ aout)
{
    __shared__ __align__(16) _Float16 Klds[NS][8];    // 16 KB, scaled by SQRT_ALPHA
    __shared__ __align__(16) _Float16 Vt[9][1036];    // 18.2 KB: rows0-7 raw k, row8 ones
    __shared__ __align__(16) float4 scratch[8][64];   // 8 KB: key-half-1 partials

    const int t    = threadIdx.x;
    const int blk  = blockIdx.x;
    const int qt   = blk & 7;          // 128-query tile
    const int bh   = blk >> 3;
    const int b    = bh >> 4;
    const int h    = bh & 15;
    const int lane = t & 63;
    const int w    = t >> 6;           // 0..15
    const int qsub = w & 7;            // 16-query subtile
    const int kh   = w >> 3;           // key half: [kh*512, kh*512+512)

    const float ph0 = phi[0], ph1 = phi[1], ph2 = phi[2], ph3 = phi[3];
    const float ph4 = phi[4], ph5 = phi[5], ph6 = phi[6], ph7 = phi[7];

    // ---- stage K (scaled) and V^T (raw + ones row): one row per thread ----
    {
        const int k = t;
        const float* xr = x + ((size_t)(b * NS + k)) * NE + h * ND;
        float4 xa = *(const float4*)xr;
        float4 xc = *(const float4*)(xr + 4);
        float g0 = __cosf(xa.x + ph0), g1 = __cosf(xa.y + ph1);
        float g2 = __cosf(xa.z + ph2), g3 = __cosf(xa.w + ph3);
        float g4 = __cosf(xc.x + ph4), g5 = __cosf(xc.y + ph5);
        float g6 = __cosf(xc.z + ph6), g7 = __cosf(xc.w + ph7);
        float s7 = g7, s6 = s7 * g6, s5 = s6 * g5, s4 = s5 * g4, s3 = s4 * g3, s2 = s3 * g2;
        float v0 = s2 * g1;                         // wire 0 expectation
        float v1 = g0 * g1, v2 = v1 * g2, v3 = v2 * g3;
        float v4 = v3 * g4, v5 = v4 * g5, v6 = v5 * g6, v7 = v6 * g7;
        half8v row;
        row[0] = (_Float16)(SQRT_ALPHA * v0); row[1] = (_Float16)(SQRT_ALPHA * v1);
        row[2] = (_Float16)(SQRT_ALPHA * v2); row[3] = (_Float16)(SQRT_ALPHA * v3);
        row[4] = (_Float16)(SQRT_ALPHA * v4); row[5] = (_Float16)(SQRT_ALPHA * v5);
        row[6] = (_Float16)(SQRT_ALPHA * v6); row[7] = (_Float16)(SQRT_ALPHA * v7);
        *(half8v*)&Klds[k][0] = row;
        Vt[0][k] = (_Float16)v0; Vt[1][k] = (_Float16)v1;
        Vt[2][k] = (_Float16)v2; Vt[3][k] = (_Float16)v3;
        Vt[4][k] = (_Float16)v4; Vt[5][k] = (_Float16)v5;
        Vt[6][k] = (_Float16)v6; Vt[7][k] = (_Float16)v7;
        Vt[8][k] = (_Float16)1.0f;
    }
    __syncthreads();

    const int e = lane & 15;
    const int g = lane >> 4;

    // Q fragment (B operand of S^T): B[kd][q], kd=(l>>4)*4+j, q=l&15.
    // Lanes >=32 cover kd 8..15 -> zero (kills garbage K products too).
    half4v qf = (half4v)(_Float16)0.0f;
    if (lane < 32) {
        int qrow = qt * 128 + qsub * 16 + e;
        qf = *(const half4v*)&Klds[qrow][g * 4];
    }

    const _Float16* kp = &Klds[kh * 512 + e][(g & 1) * 4];  // A: K[koff+tt*16+(l&15)][(l>>4)*4+j]
    const int ecl = (e > 8) ? 8 : e;                        // clamp: cols 9..15 unread
    const _Float16* vp = &Vt[ecl][kh * 512 + g * 4];        // B_V: V[koff+tt*16+(l>>4)*4+j][e]

    float4v acc = (float4v)0.0f;
    const float4v zero = (float4v)0.0f;

#pragma unroll 8
    for (int tt = 0; tt < 32; ++tt) {
        half4v kf = *(const half4v*)(kp + tt * 128);   // 16 rows * 8 halves
        half4v vf = *(const half4v*)(vp + tt * 16);
        float4v s = __builtin_amdgcn_mfma_f32_16x16x16f16(kf, qf, zero, 0, 0, 0);
        float p0 = EXP2F(s[0]);
        float p1 = EXP2F(s[1]);
        float p2 = EXP2F(s[2]);
        float p3 = EXP2F(s[3]);
        half2v lo = __builtin_bit_cast(half2v, __builtin_amdgcn_cvt_pkrtz(p0, p1));
        half2v hi = __builtin_bit_cast(half2v, __builtin_amdgcn_cvt_pkrtz(p2, p3));
        half4v pa = __builtin_shufflevector(lo, hi, 0, 1, 2, 3);
        acc = __builtin_amdgcn_mfma_f32_16x16x16f16(pa, vf, acc, 0, 0, 0);
    }

    // ---- combine key-half partials: waves 8..15 -> LDS, waves 0..7 add ----
    if (kh == 1) {
        scratch[qsub][lane] = make_float4(acc[0], acc[1], acc[2], acc[3]);
    }
    __syncthreads();
    if (kh == 0) {
        float4 c = scratch[qsub][lane];
        acc[0] += c.x; acc[1] += c.y; acc[2] += c.z; acc[3] += c.w;

        // ---- normalize by column 8 (softmax denom) and store ----
        const int src = (lane & 48) | 8;
        float d0 = __shfl(acc[0], src, 64);
        float d1 = __shfl(acc[1], src, 64);
        float d2 = __shfl(acc[2], src, 64);
        float d3 = __shfl(acc[3], src, 64);
        float o0 = acc[0] / d0, o1 = acc[1] / d1;
        float o2 = acc[2] / d2, o3 = acc[3] / d3;
        if (e < 8) {
            size_t rbase = (size_t)(b * NS + qt * 128 + qsub * 16 + g * 4);
            float* op = aout + rbase * NE + h * ND + e;
            op[0 * NE] = o0;
            op[1 * NE] = o1;
            op[2 * NE] = o2;
            op[3 * NE] = o3;
        }
    }
}

// ---------------------------------------------------------------------------
// out = A @ W^T + b, in place (block reads only the 16 rows it writes).
// 256 blocks x 512 thr. W transposed-staged in two 64-col halves.
// ---------------------------------------------------------------------------
__global__ __launch_bounds__(512)
void proj_kernel(const float* __restrict__ A, const float* __restrict__ W,
                 const float* __restrict__ bias, float* __restrict__ out)
{
    __shared__ float Wt[64][NE + 4];   // transposed half of W, padded (33.8 KB)
    __shared__ float As[16][NE];       // 8 KB

    const int t  = threadIdx.x;
    const int r0 = blockIdx.x * 16;

    for (int i = t; i < 16 * NE; i += 512) {
        As[i >> 7][i & 127] = A[(size_t)(r0 + (i >> 7)) * NE + (i & 127)];
    }

    const int c4 = (t & 31) * 4;
    const int rg = t >> 5;                     // row r0+rg (0..15)
    float acc0 = 0, acc1 = 0, acc2 = 0, acc3 = 0;

    for (int eh = 0; eh < 2; ++eh) {
        if (eh) __syncthreads();               // previous half fully consumed
        for (int i = t; i < NE * 64; i += 512) {
            int c = i >> 6;
            int e = i & 63;
            Wt[e][c] = W[c * NE + eh * 64 + e];
        }
        __syncthreads();
#pragma unroll 8
        for (int e = 0; e < 64; ++e) {
            float4 wv = *(const float4*)&Wt[e][c4];
            float av = As[rg][eh * 64 + e];
            acc0 += av * wv.x; acc1 += av * wv.y;
            acc2 += av * wv.z; acc3 += av * wv.w;
        }
    }

    float4 bv = *(const float4*)&bias[c4];
    float4 o = make_float4(acc0 + bv.x, acc1 + bv.y, acc2 + bv.z, acc3 + bv.w);
    *(float4*)(out + (size_t)(r0 + rg) * NE + c4) = o;
}

extern "C" void kernel_launch(void* const* d_in, const int* in_sizes, int n_in,
                              void* d_out, int out_size, void* d_ws, size_t ws_size,
                              hipStream_t stream)
{
    (void)in_sizes; (void)n_in; (void)out_size; (void)d_ws; (void)ws_size;
    const float* x   = (const float*)d_in[0];
    const float* phi = (const float*)d_in[1];
    const float* W   = (const float*)d_in[2];
    const float* b   = (const float*)d_in[3];
    float* out = (float*)d_out;

    qattn_kernel<<<dim3(NB * NH * 8), dim3(1024), 0, stream>>>(x, phi, out);
    proj_kernel<<<dim3(NB * NS / 16), dim3(512), 0, stream>>>(out, W, b, out);
}

// Round 8
// 24.087 us; speedup vs baseline: 1.0731x; 1.0731x over previous
//
#include <hip/hip_runtime.h>

#define NB 4
#define NS 1024
#define NE 128
#define NH 16
#define ND 8

typedef __attribute__((ext_vector_type(4))) _Float16 half4v;
typedef __attribute__((ext_vector_type(8))) _Float16 half8v;
typedef __attribute__((ext_vector_type(2))) _Float16 half2v;
typedef __attribute__((ext_vector_type(4))) float float4v;

// 2^x with BOTH branches native: builtin v_exp_f32 if available, else
// __expf(ln2*x) = v_mul_f32 + v_exp_f32 (never the ocml libm path).
#if __has_builtin(__builtin_amdgcn_exp2f)
#define EXP2F(x) __builtin_amdgcn_exp2f(x)
#else
#define EXP2F(x) __expf(0.69314718055994531f * (x))
#endif

// sqrt(log2(e)/sqrt(8)): both QK^T operands carry this -> MFMA out feeds 2^x directly
#define SQRT_ALPHA 0.71423656f

// ---------------------------------------------------------------------------
// Fused quantum-layer + self-attention via f16 MFMA, key-split + phase-batched.
// proj[0]=g1*...*g7, proj[w]=g0*...*gw with g_j=cos(x_j+phi_j)  (closed form).
// S^T = K.Q^T via mfma 16x16x16: lane holds P[q=l&15][keys (l>>4)*4+r] ->
// exactly the PV A-fragment after exp2+cvt_pkrtz (no LDS bounce for P).
// V staged transposed with a ones-row (col 8 of output = softmax denom).
// Block = 1024 thr = 16 waves: wave w -> q-subtile (w&7), key half (w>>3).
// __launch_bounds__(1024, 8): VGPR<=64 hard cap -> 2 blocks/CU resident
// (32 waves/CU, 8/SIMD) — R6 likely missed this and ran at 4/SIMD.
// Main loop phase-batched (4 tiles): ds-cluster -> QK-MFMA cluster ->
// exp/cvt cluster -> PV-MFMA cluster; one MFMA-wait per 4 tiles, long TRANS
// bursts that interleave with other waves' MFMA phases.
// ---------------------------------------------------------------------------
__global__ __launch_bounds__(1024, 8)
void qattn_kernel(const float* __restrict__ x, const float* __restrict__ phi,
                  float* __restrict__ aout)
{
    __shared__ __align__(16) _Float16 Klds[NS][8];    // 16 KB, scaled by SQRT_ALPHA
    __shared__ __align__(16) _Float16 Vt[9][1036];    // 18.2 KB: rows0-7 raw k, row8 ones
    __shared__ __align__(16) float4 scratch[8][64];   // 8 KB: key-half-1 partials

    const int t    = threadIdx.x;
    const int blk  = blockIdx.x;
    const int qt   = blk & 7;          // 128-query tile
    const int bh   = blk >> 3;
    const int b    = bh >> 4;
    const int h    = bh & 15;
    const int lane = t & 63;
    const int w    = t >> 6;           // 0..15
    const int qsub = w & 7;            // 16-query subtile
    const int kh   = w >> 3;           // key half: [kh*512, kh*512+512)

    const float ph0 = phi[0], ph1 = phi[1], ph2 = phi[2], ph3 = phi[3];
    const float ph4 = phi[4], ph5 = phi[5], ph6 = phi[6], ph7 = phi[7];

    // ---- stage K (scaled) and V^T (raw + ones row): one row per thread ----
    {
        const int k = t;
        const float* xr = x + ((size_t)(b * NS + k)) * NE + h * ND;
        float4 xa = *(const float4*)xr;
        float4 xc = *(const float4*)(xr + 4);
        float g0 = __cosf(xa.x + ph0), g1 = __cosf(xa.y + ph1);
        float g2 = __cosf(xa.z + ph2), g3 = __cosf(xa.w + ph3);
        float g4 = __cosf(xc.x + ph4), g5 = __cosf(xc.y + ph5);
        float g6 = __cosf(xc.z + ph6), g7 = __cosf(xc.w + ph7);
        float s7 = g7, s6 = s7 * g6, s5 = s6 * g5, s4 = s5 * g4, s3 = s4 * g3, s2 = s3 * g2;
        float v0 = s2 * g1;                         // wire 0 expectation
        float v1 = g0 * g1, v2 = v1 * g2, v3 = v2 * g3;
        float v4 = v3 * g4, v5 = v4 * g5, v6 = v5 * g6, v7 = v6 * g7;
        half8v row;
        row[0] = (_Float16)(SQRT_ALPHA * v0); row[1] = (_Float16)(SQRT_ALPHA * v1);
        row[2] = (_Float16)(SQRT_ALPHA * v2); row[3] = (_Float16)(SQRT_ALPHA * v3);
        row[4] = (_Float16)(SQRT_ALPHA * v4); row[5] = (_Float16)(SQRT_ALPHA * v5);
        row[6] = (_Float16)(SQRT_ALPHA * v6); row[7] = (_Float16)(SQRT_ALPHA * v7);
        *(half8v*)&Klds[k][0] = row;
        Vt[0][k] = (_Float16)v0; Vt[1][k] = (_Float16)v1;
        Vt[2][k] = (_Float16)v2; Vt[3][k] = (_Float16)v3;
        Vt[4][k] = (_Float16)v4; Vt[5][k] = (_Float16)v5;
        Vt[6][k] = (_Float16)v6; Vt[7][k] = (_Float16)v7;
        Vt[8][k] = (_Float16)1.0f;
    }
    __syncthreads();

    const int e = lane & 15;
    const int g = lane >> 4;

    // Q fragment (B operand of S^T): B[kd][q], kd=(l>>4)*4+j, q=l&15.
    // Lanes >=32 cover kd 8..15 -> zero (kills garbage K products too).
    half4v qf = (half4v)(_Float16)0.0f;
    if (lane < 32) {
        int qrow = qt * 128 + qsub * 16 + e;
        qf = *(const half4v*)&Klds[qrow][g * 4];
    }

    const _Float16* kp = &Klds[kh * 512 + e][(g & 1) * 4];  // A: K[koff+tt*16+(l&15)][(l>>4)*4+j]
    const int ecl = (e > 8) ? 8 : e;                        // clamp: cols 9..15 unread
    const _Float16* vp = &Vt[ecl][kh * 512 + g * 4];        // B_V: V[koff+tt*16+(l>>4)*4+j][e]

    float4v acc = (float4v)0.0f;
    const float4v zero = (float4v)0.0f;

    // 8 batches x 4 tiles x 16 keys = 512 keys. Phase clusters within a batch.
    for (int batch = 0; batch < 8; ++batch) {
        const _Float16* kpb = kp + batch * 512;   // 4 tiles * 128 halves
        const _Float16* vpb = vp + batch * 64;    // 4 tiles * 16 halves

        half4v kf0 = *(const half4v*)(kpb);
        half4v kf1 = *(const half4v*)(kpb + 128);
        half4v kf2 = *(const half4v*)(kpb + 256);
        half4v kf3 = *(const half4v*)(kpb + 384);
        half4v vf0 = *(const half4v*)(vpb);
        half4v vf1 = *(const half4v*)(vpb + 16);
        half4v vf2 = *(const half4v*)(vpb + 32);
        half4v vf3 = *(const half4v*)(vpb + 48);

        float4v s0 = __builtin_amdgcn_mfma_f32_16x16x16f16(kf0, qf, zero, 0, 0, 0);
        float4v s1 = __builtin_amdgcn_mfma_f32_16x16x16f16(kf1, qf, zero, 0, 0, 0);
        float4v s2 = __builtin_amdgcn_mfma_f32_16x16x16f16(kf2, qf, zero, 0, 0, 0);
        float4v s3 = __builtin_amdgcn_mfma_f32_16x16x16f16(kf3, qf, zero, 0, 0, 0);

        float p00 = EXP2F(s0[0]), p01 = EXP2F(s0[1]), p02 = EXP2F(s0[2]), p03 = EXP2F(s0[3]);
        float p10 = EXP2F(s1[0]), p11 = EXP2F(s1[1]), p12 = EXP2F(s1[2]), p13 = EXP2F(s1[3]);
        float p20 = EXP2F(s2[0]), p21 = EXP2F(s2[1]), p22 = EXP2F(s2[2]), p23 = EXP2F(s2[3]);
        float p30 = EXP2F(s3[0]), p31 = EXP2F(s3[1]), p32 = EXP2F(s3[2]), p33 = EXP2F(s3[3]);

        half2v lo0 = __builtin_bit_cast(half2v, __builtin_amdgcn_cvt_pkrtz(p00, p01));
        half2v hi0 = __builtin_bit_cast(half2v, __builtin_amdgcn_cvt_pkrtz(p02, p03));
        half2v lo1 = __builtin_bit_cast(half2v, __builtin_amdgcn_cvt_pkrtz(p10, p11));
        half2v hi1 = __builtin_bit_cast(half2v, __builtin_amdgcn_cvt_pkrtz(p12, p13));
        half2v lo2 = __builtin_bit_cast(half2v, __builtin_amdgcn_cvt_pkrtz(p20, p21));
        half2v hi2 = __builtin_bit_cast(half2v, __builtin_amdgcn_cvt_pkrtz(p22, p23));
        half2v lo3 = __builtin_bit_cast(half2v, __builtin_amdgcn_cvt_pkrtz(p30, p31));
        half2v hi3 = __builtin_bit_cast(half2v, __builtin_amdgcn_cvt_pkrtz(p32, p33));
        half4v pa0 = __builtin_shufflevector(lo0, hi0, 0, 1, 2, 3);
        half4v pa1 = __builtin_shufflevector(lo1, hi1, 0, 1, 2, 3);
        half4v pa2 = __builtin_shufflevector(lo2, hi2, 0, 1, 2, 3);
        half4v pa3 = __builtin_shufflevector(lo3, hi3, 0, 1, 2, 3);

        acc = __builtin_amdgcn_mfma_f32_16x16x16f16(pa0, vf0, acc, 0, 0, 0);
        acc = __builtin_amdgcn_mfma_f32_16x16x16f16(pa1, vf1, acc, 0, 0, 0);
        acc = __builtin_amdgcn_mfma_f32_16x16x16f16(pa2, vf2, acc, 0, 0, 0);
        acc = __builtin_amdgcn_mfma_f32_16x16x16f16(pa3, vf3, acc, 0, 0, 0);
    }

    // ---- combine key-half partials: waves 8..15 -> LDS, waves 0..7 add ----
    if (kh == 1) {
        scratch[qsub][lane] = make_float4(acc[0], acc[1], acc[2], acc[3]);
    }
    __syncthreads();
    if (kh == 0) {
        float4 c = scratch[qsub][lane];
        acc[0] += c.x; acc[1] += c.y; acc[2] += c.z; acc[3] += c.w;

        // ---- normalize by column 8 (softmax denom) and store ----
        const int src = (lane & 48) | 8;
        float d0 = __shfl(acc[0], src, 64);
        float d1 = __shfl(acc[1], src, 64);
        float d2 = __shfl(acc[2], src, 64);
        float d3 = __shfl(acc[3], src, 64);
        float o0 = acc[0] / d0, o1 = acc[1] / d1;
        float o2 = acc[2] / d2, o3 = acc[3] / d3;
        if (e < 8) {
            size_t rbase = (size_t)(b * NS + qt * 128 + qsub * 16 + g * 4);
            float* op = aout + rbase * NE + h * ND + e;
            op[0 * NE] = o0;
            op[1 * NE] = o1;
            op[2 * NE] = o2;
            op[3 * NE] = o3;
        }
    }
}

// ---------------------------------------------------------------------------
// out = A @ W^T + b, in place (block reads only the 16 rows it writes).
// 256 blocks x 512 thr. W transposed-staged in two 64-col halves.
// ---------------------------------------------------------------------------
__global__ __launch_bounds__(512)
void proj_kernel(const float* __restrict__ A, const float* __restrict__ W,
                 const float* __restrict__ bias, float* __restrict__ out)
{
    __shared__ float Wt[64][NE + 4];   // transposed half of W, padded (33.8 KB)
    __shared__ float As[16][NE];       // 8 KB

    const int t  = threadIdx.x;
    const int r0 = blockIdx.x * 16;

    for (int i = t; i < 16 * NE; i += 512) {
        As[i >> 7][i & 127] = A[(size_t)(r0 + (i >> 7)) * NE + (i & 127)];
    }

    const int c4 = (t & 31) * 4;
    const int rg = t >> 5;                     // row r0+rg (0..15)
    float acc0 = 0, acc1 = 0, acc2 = 0, acc3 = 0;

    for (int eh = 0; eh < 2; ++eh) {
        if (eh) __syncthreads();               // previous half fully consumed
        for (int i = t; i < NE * 64; i += 512) {
            int c = i >> 6;
            int e = i & 63;
            Wt[e][c] = W[c * NE + eh * 64 + e];
        }
        __syncthreads();
#pragma unroll 8
        for (int e = 0; e < 64; ++e) {
            float4 wv = *(const float4*)&Wt[e][c4];
            float av = As[rg][eh * 64 + e];
            acc0 += av * wv.x; acc1 += av * wv.y;
            acc2 += av * wv.z; acc3 += av * wv.w;
        }
    }

    float4 bv = *(const float4*)&bias[c4];
    float4 o = make_float4(acc0 + bv.x, acc1 + bv.y, acc2 + bv.z, acc3 + bv.w);
    *(float4*)(out + (size_t)(r0 + rg) * NE + c4) = o;
}

extern "C" void kernel_launch(void* const* d_in, const int* in_sizes, int n_in,
                              void* d_out, int out_size, void* d_ws, size_t ws_size,
                              hipStream_t stream)
{
    (void)in_sizes; (void)n_in; (void)out_size; (void)d_ws; (void)ws_size;
    const float* x   = (const float*)d_in[0];
    const float* phi = (const float*)d_in[1];
    const float* W   = (const float*)d_in[2];
    const float* b   = (const float*)d_in[3];
    float* out = (float*)d_out;

    qattn_kernel<<<dim3(NB * NH * 8), dim3(1024), 0, stream>>>(x, phi, out);
    proj_kernel<<<dim3(NB * NS / 16), dim3(512), 0, stream>>>(out, W, b, out);
}